// Round 4
// baseline (288.361 us; speedup 1.0000x reference)
//
#include <hip/hip_runtime.h>
#include <hip/hip_bf16.h>
#include <stdint.h>

typedef __bf16 bf16x8 __attribute__((ext_vector_type(8)));
typedef float floatx4 __attribute__((ext_vector_type(4)));

// ---------------------------------------------------------------------------
// Async global->LDS 16B copy (wave-uniform LDS base + lane*16; per-lane
// global address OK).
// ---------------------------------------------------------------------------
__device__ __forceinline__ void async_copy16(void* lds, const void* g) {
    __builtin_amdgcn_global_load_lds(
        (const __attribute__((address_space(1))) unsigned int*)g,
        (__attribute__((address_space(3))) unsigned int*)lds,
        16, 0, 0);
}

__device__ __forceinline__ bf16x8 cvt8(float4 u, float4 v) {
    bf16x8 r;
    r[0] = (__bf16)u.x; r[1] = (__bf16)u.y; r[2] = (__bf16)u.z; r[3] = (__bf16)u.w;
    r[4] = (__bf16)v.x; r[5] = (__bf16)v.y; r[6] = (__bf16)v.z; r[7] = (__bf16)v.w;
    return r;
}

// ---------------------------------------------------------------------------
// prep r10: KRON-ONLY (the x->bf16 conversion pass is FUSED into the gemm's
// A-staging now -> saves 126 MB of traffic + one serialized dispatch).
//   blocks [0,1280): Wrot[o,d] = sum_k kron(K1,K2,K3)[d,k] W[o,k]
// ---------------------------------------------------------------------------
__global__ __launch_bounds__(256)
void prep(const float* __restrict__ W,
          const float* __restrict__ K1,
          const float* __restrict__ K2,
          const float* __restrict__ K3,
          __hip_bfloat16* __restrict__ Wrot) {
    const int tid = threadIdx.x;
    const int o = blockIdx.x;
    __shared__ __align__(16) float w0[1280];   // W row, then stage-2 result
    __shared__ __align__(16) float t1[1280];
    __shared__ __align__(16) float k3s[1600];
    __shared__ float k2s[64];
    __shared__ float k1s[16];

    for (int i = tid; i < 1280; i += 256) w0[i] = W[o * 1280 + i];
    for (int i = tid; i < 1600; i += 256) k3s[i] = K3[i];
    if (tid < 64) k2s[tid] = K2[tid];
    if (tid < 16) k1s[tid] = K1[tid];
    __syncthreads();

    for (int i = tid; i < 1280; i += 256) {
        const int p = i / 40, d3 = i % 40;
        const float4* w4 = (const float4*)(w0 + p * 40);
        const float4* k4 = (const float4*)(k3s + d3 * 40);
        float acc = 0.f;
#pragma unroll
        for (int t = 0; t < 10; ++t) {
            const float4 a = w4[t], b = k4[t];
            acc += a.x * b.x + a.y * b.y + a.z * b.z + a.w * b.w;
        }
        t1[i] = acc;
    }
    __syncthreads();

    for (int i = tid; i < 1280; i += 256) {
        const int d3 = i % 40, pd = i / 40;
        const int k1 = pd >> 3, d2 = pd & 7;
        float acc = 0.f;
#pragma unroll
        for (int k2 = 0; k2 < 8; ++k2) acc += t1[(k1 * 8 + k2) * 40 + d3] * k2s[d2 * 8 + k2];
        w0[i] = acc;
    }
    __syncthreads();

    for (int i = tid; i < 1280; i += 256) {
        const int d3 = i % 40, pd = i / 40;
        const int d1 = pd >> 3, d2 = pd & 7;
        float acc = 0.f;
#pragma unroll
        for (int k1 = 0; k1 < 4; ++k1) acc += w0[(k1 * 8 + d2) * 40 + d3] * k1s[d1 * 4 + k1];
        Wrot[(size_t)o * 1280 + i] = __float2bfloat16(acc);
    }
}

// ---------------------------------------------------------------------------
// Main GEMM r10: C[m,n] = sum_k X[m,k] * B[n,k]  (X fp32 in! bf16 MFMA,
// fp32 out/acc).  r9 skeleton (4-phase interleave, dbuf, XOR swizzle,
// 256-block XCD grid) with A-staging FUSED with the fp32->bf16 convert:
//   - A path: fp32 x -> 2x global_load_dwordx4 to regs (T14 issue-early:
//     A0/A1 at ph0, A2/A3 at ph1) -> cvt to bf16 -> ds_write_b128 into the
//     SAME XOR-swizzled granules one phase later (A0/A1 @ph1, A2/A3 @ph2).
//     Same cast, same granules, same accumulate order as r9 -> bitwise
//     identical output.  Live-reg cost capped at +16 VGPR (half-split).
//   - B path: unchanged global_load_lds (B0@ph0, B1,B2@ph1, B3,B4@ph2).
//   - Waits: compiler's waitcnt pass handles the A-reg cvts exactly (it
//     models gload_lds in vmcnt too).  Manual waits only at end of ph3:
//     vmcnt(0) (B lands; B4 has ~2 phases of lead) + lgkmcnt(0) (ds_write
//     visibility across the iter-boundary barrier).  No mid-loop counted
//     vmcnt needed anymore.
// ---------------------------------------------------------------------------
#define BM 256
#define BN 320
#define BK 64
#define AGRAN 2048   // BM*8 granules (16B each) per buffer = 32 KiB
#define BGRAN 2560   // BN*8 granules per buffer = 40 KiB

__global__ __launch_bounds__(512, 2)
void gemm_bt(const float* __restrict__ X,            // [M,K] fp32
             const __hip_bfloat16* __restrict__ B,   // [N,K] bf16
             float* __restrict__ C,                  // [M,N] fp32
             int M, int N, int K) {
    __shared__ bf16x8 As[2][AGRAN];   // 64 KiB
    __shared__ bf16x8 Bs[2][BGRAN];   // 80 KiB

    const int tid  = threadIdx.x;
    const int wave = tid >> 6;
    const int lane = tid & 63;
    const int q    = lane >> 4;
    const int r16  = lane & 15;
    const int wm   = wave >> 2;       // 0..1
    const int wn   = wave & 3;        // 0..3

    // XCD-partitioned tile assignment (grid = 64*4 = 256, 8 | 256)
    const int nTilesN = N / BN;               // 4
    const int chunkM  = (M / BM) >> 3;        // 8 M-tiles per XCD
    const int xcd = blockIdx.x & 7;
    const int s   = blockIdx.x >> 3;          // 0..31 within XCD
    const int bm  = xcd * chunkM + s / nTilesN;
    const int bn  = s % nTilesN;
    const int tileM = bm * BM, tileN = bn * BN;

    // Per-chunk global BYTE offsets. chunk c covers granules [c*512,+512):
    // granule g: row m = g>>3, phys slot p = g&7 holds data k-granule
    // kv = p ^ (m&7)  (XOR swizzle at source).  A is fp32 (x4B), B bf16 (x2B).
    uint32_t aoff[4], boff[5];
#pragma unroll
    for (int c = 0; c < 4; ++c) {
        const int g = c * 512 + tid;
        const int m = g >> 3, kv = (g & 7) ^ (m & 7);
        aoff[c] = (uint32_t)(((tileM + m) * K + kv * 8) * 4);
    }
#pragma unroll
    for (int c = 0; c < 5; ++c) {
        const int g = c * 512 + tid;
        const int m = g >> 3, kv = (g & 7) ^ (m & 7);
        boff[c] = (uint32_t)(((tileN + m) * K + kv * 8) * 2);
    }
    const char* Xb = (const char*)X;
    const char* Bb = (const char*)B;

    // LDS fragment granule indices for k-slice 0; k-slice 1 = idx ^ 4.
    int ai[8], bi[5];
#pragma unroll
    for (int i = 0; i < 8; ++i) {
        const int m = wm * 128 + i * 16 + r16;
        ai[i] = m * 8 + (q ^ (m & 7));
    }
#pragma unroll
    for (int j = 0; j < 5; ++j) {
        const int n = wn * 80 + j * 16 + r16;
        bi[j] = n * 8 + (q ^ (n & 7));
    }

    floatx4 acc[8][5];
#pragma unroll
    for (int i = 0; i < 8; ++i)
#pragma unroll
        for (int j = 0; j < 5; ++j) acc[i][j] = (floatx4){0.f, 0.f, 0.f, 0.f};

    const int nk = K / BK;                    // 20

    // Prologue: stage tile 0.  A: reg-load fp32 -> cvt -> ds_write; B: lds.
    {
        float4 p0, p1;
#pragma unroll
        for (int c = 0; c < 5; ++c)
            async_copy16(&Bs[0][c * 512 + wave * 64], Bb + boff[c]);
#pragma unroll
        for (int c = 0; c < 4; ++c) {
            p0 = *(const float4*)(Xb + aoff[c]);
            p1 = *(const float4*)(Xb + aoff[c] + 16);
            As[0][c * 512 + tid] = cvt8(p0, p1);
        }
        asm volatile("s_waitcnt vmcnt(0)" ::: "memory");
        asm volatile("s_waitcnt lgkmcnt(0)" ::: "memory");
        __builtin_amdgcn_s_barrier();
    }

    bf16x8 bf0[5], bf1[5], af[4];
    float4 a0, a1, a2, a3, a4, a5, a6, a7;    // staged A regs (2 halves)

    for (int t = 0; t < nk; ++t) {
        const int cur = t & 1, nxt = cur ^ 1;
        const uint32_t kbA = (uint32_t)((t + 1) * BK * 4);
        const uint32_t kbB = (uint32_t)((t + 1) * BK * 2);
        const bool hn = (t + 1 < nk);

        // ---------------- phase 0: k-slice 0, rows i=0..3 ----------------
#pragma unroll
        for (int i = 0; i < 4; ++i) af[i] = As[cur][ai[i]];
#pragma unroll
        for (int j = 0; j < 5; ++j) bf0[j] = Bs[cur][bi[j]];
        if (hn) {
            a0 = *(const float4*)(Xb + aoff[0] + kbA);
            a1 = *(const float4*)(Xb + aoff[0] + kbA + 16);
            a2 = *(const float4*)(Xb + aoff[1] + kbA);
            a3 = *(const float4*)(Xb + aoff[1] + kbA + 16);
            async_copy16(&Bs[nxt][0 * 512 + wave * 64], Bb + boff[0] + kbB);
        }
        __builtin_amdgcn_sched_barrier(0);
        __builtin_amdgcn_s_barrier();
        __builtin_amdgcn_sched_barrier(0);
        __builtin_amdgcn_s_setprio(1);
#pragma unroll
        for (int j = 0; j < 5; ++j)
#pragma unroll
            for (int i = 0; i < 4; ++i)
                acc[i][j] = __builtin_amdgcn_mfma_f32_16x16x32_bf16(
                    af[i], bf0[j], acc[i][j], 0, 0, 0);
        __builtin_amdgcn_s_setprio(0);
        __builtin_amdgcn_sched_barrier(0);
        __builtin_amdgcn_s_barrier();

        // ---------------- phase 1: k-slice 1, rows i=0..3 ----------------
#pragma unroll
        for (int i = 0; i < 4; ++i) af[i] = As[cur][ai[i] ^ 4];
#pragma unroll
        for (int j = 0; j < 5; ++j) bf1[j] = Bs[cur][bi[j] ^ 4];
        if (hn) {
            a4 = *(const float4*)(Xb + aoff[2] + kbA);
            a5 = *(const float4*)(Xb + aoff[2] + kbA + 16);
            a6 = *(const float4*)(Xb + aoff[3] + kbA);
            a7 = *(const float4*)(Xb + aoff[3] + kbA + 16);
            async_copy16(&Bs[nxt][1 * 512 + wave * 64], Bb + boff[1] + kbB);
            async_copy16(&Bs[nxt][2 * 512 + wave * 64], Bb + boff[2] + kbB);
            // cvt+write first A half (loads have ~1 phase of lead; compiler
            // inserts the exact partial vmcnt here)
            As[nxt][0 * 512 + tid] = cvt8(a0, a1);
            As[nxt][1 * 512 + tid] = cvt8(a2, a3);
        }
        __builtin_amdgcn_sched_barrier(0);
        __builtin_amdgcn_s_barrier();
        __builtin_amdgcn_sched_barrier(0);
        __builtin_amdgcn_s_setprio(1);
#pragma unroll
        for (int j = 0; j < 5; ++j)
#pragma unroll
            for (int i = 0; i < 4; ++i)
                acc[i][j] = __builtin_amdgcn_mfma_f32_16x16x32_bf16(
                    af[i], bf1[j], acc[i][j], 0, 0, 0);
        __builtin_amdgcn_s_setprio(0);
        __builtin_amdgcn_sched_barrier(0);
        __builtin_amdgcn_s_barrier();

        // ---------------- phase 2: k-slice 0, rows i=4..7 ----------------
#pragma unroll
        for (int i = 0; i < 4; ++i) af[i] = As[cur][ai[4 + i]];
        if (hn) {
            async_copy16(&Bs[nxt][3 * 512 + wave * 64], Bb + boff[3] + kbB);
            async_copy16(&Bs[nxt][4 * 512 + wave * 64], Bb + boff[4] + kbB);
            As[nxt][2 * 512 + tid] = cvt8(a4, a5);
            As[nxt][3 * 512 + tid] = cvt8(a6, a7);
        }
        __builtin_amdgcn_sched_barrier(0);
        __builtin_amdgcn_s_barrier();
        __builtin_amdgcn_sched_barrier(0);
        __builtin_amdgcn_s_setprio(1);
#pragma unroll
        for (int i = 0; i < 4; ++i)
#pragma unroll
            for (int j = 0; j < 5; ++j)
                acc[4 + i][j] = __builtin_amdgcn_mfma_f32_16x16x32_bf16(
                    af[i], bf0[j], acc[4 + i][j], 0, 0, 0);
        __builtin_amdgcn_s_setprio(0);
        __builtin_amdgcn_sched_barrier(0);
        __builtin_amdgcn_s_barrier();

        // ---------------- phase 3: k-slice 1, rows i=4..7 ----------------
#pragma unroll
        for (int i = 0; i < 4; ++i) af[i] = As[cur][ai[4 + i] ^ 4];
        __builtin_amdgcn_sched_barrier(0);
        __builtin_amdgcn_s_barrier();
        __builtin_amdgcn_sched_barrier(0);
        __builtin_amdgcn_s_setprio(1);
#pragma unroll
        for (int i = 0; i < 4; ++i)
#pragma unroll
            for (int j = 0; j < 5; ++j)
                acc[4 + i][j] = __builtin_amdgcn_mfma_f32_16x16x32_bf16(
                    af[i], bf1[j], acc[4 + i][j], 0, 0, 0);
        __builtin_amdgcn_s_setprio(0);
        __builtin_amdgcn_sched_barrier(0);
        if (hn) {
            // B0..B4 of tile t+1 land (B4 had ~2 phases of lead); ds_writes
            // of A(t+1) become visible across the iter-boundary barrier.
            asm volatile("s_waitcnt vmcnt(0)" ::: "memory");
            asm volatile("s_waitcnt lgkmcnt(0)" ::: "memory");
        }
        __builtin_amdgcn_sched_barrier(0);
        __builtin_amdgcn_s_barrier();
    }

    // epilogue: C/D layout col=lane&15, row=quad*4+reg (m89/m91)
#pragma unroll
    for (int i = 0; i < 8; ++i) {
#pragma unroll
        for (int j = 0; j < 5; ++j) {
            const int col = tileN + wn * 80 + j * 16 + r16;
#pragma unroll
            for (int r = 0; r < 4; ++r) {
                const int row = tileM + wm * 128 + i * 16 + q * 4 + r;
                C[(size_t)row * N + col] = acc[i][j][r];
            }
        }
    }
}

// ---------------------------------------------------------------------------
extern "C" void kernel_launch(void* const* d_in, const int* in_sizes, int n_in,
                              void* d_out, int out_size, void* d_ws, size_t ws_size,
                              hipStream_t stream) {
    const float* x  = (const float*)d_in[0];  // [4,4096,1280] fp32
    const float* W  = (const float*)d_in[1];  // [1280,1280]  fp32
    const float* K1 = (const float*)d_in[2];  // [4,4]
    const float* K2 = (const float*)d_in[3];  // [8,8]
    const float* K3 = (const float*)d_in[4];  // [40,40]
    float* out = (float*)d_out;               // [4,4096,1280] fp32

    const int D = 1280;
    const int M = in_sizes[0] / D;            // 16384
    const int N = D, K = D;

    // ws layout: [0, N*K) bf16 Wrot (x_bf no longer exists — fused)
    __hip_bfloat16* Wrot = (__hip_bfloat16*)d_ws;

    prep<<<D, 256, 0, stream>>>(W, K1, K2, K3, Wrot);
    gemm_bt<<<(M / BM) * (N / BN), 512, 0, stream>>>(x, Wrot, out, M, N, K);
}

// Round 5
// 225.660 us; speedup vs baseline: 1.2779x; 1.2779x over previous
//
#include <hip/hip_runtime.h>
#include <hip/hip_bf16.h>
#include <stdint.h>

typedef __bf16 bf16x8 __attribute__((ext_vector_type(8)));
typedef float floatx4 __attribute__((ext_vector_type(4)));

// ---------------------------------------------------------------------------
// Async global->LDS 16B copy (wave-uniform LDS base + lane*16; per-lane
// global address OK).
// ---------------------------------------------------------------------------
__device__ __forceinline__ void async_copy16(void* lds, const void* g) {
    __builtin_amdgcn_global_load_lds(
        (const __attribute__((address_space(1))) unsigned int*)g,
        (__attribute__((address_space(3))) unsigned int*)lds,
        16, 0, 0);
}

// ---------------------------------------------------------------------------
// Fused prep, one dispatch (REVERTED to r9 — the r10 in-GEMM fusion spilled):
//   blocks [0, nConv)         : x fp32 -> bf16 (8 elems/thread, float4 loads)
//   blocks [nConv, nConv+1280): Wrot[o,d] = sum_k kron(K1,K2,K3)[d,k] W[o,k]
// ---------------------------------------------------------------------------
__global__ __launch_bounds__(256)
void prep(const float* __restrict__ x,
          const float* __restrict__ W,
          const float* __restrict__ K1,
          const float* __restrict__ K2,
          const float* __restrict__ K3,
          __hip_bfloat16* __restrict__ x_bf,
          __hip_bfloat16* __restrict__ Wrot,
          int nConv) {
    const int tid = threadIdx.x;

    if ((int)blockIdx.x < nConv) {
        const size_t i = ((size_t)blockIdx.x * 256 + tid) * 8;
        const float4 a = *(const float4*)(x + i);
        const float4 b = *(const float4*)(x + i + 4);
        bf16x8 v;
        v[0] = (__bf16)a.x; v[1] = (__bf16)a.y; v[2] = (__bf16)a.z; v[3] = (__bf16)a.w;
        v[4] = (__bf16)b.x; v[5] = (__bf16)b.y; v[6] = (__bf16)b.z; v[7] = (__bf16)b.w;
        *(bf16x8*)((__bf16*)x_bf + i) = v;
        return;
    }

    const int o = blockIdx.x - nConv;
    __shared__ __align__(16) float w0[1280];   // W row, then stage-2 result
    __shared__ __align__(16) float t1[1280];
    __shared__ __align__(16) float k3s[1600];
    __shared__ float k2s[64];
    __shared__ float k1s[16];

    for (int i = tid; i < 1280; i += 256) w0[i] = W[o * 1280 + i];
    for (int i = tid; i < 1600; i += 256) k3s[i] = K3[i];
    if (tid < 64) k2s[tid] = K2[tid];
    if (tid < 16) k1s[tid] = K1[tid];
    __syncthreads();

    for (int i = tid; i < 1280; i += 256) {
        const int p = i / 40, d3 = i % 40;
        const float4* w4 = (const float4*)(w0 + p * 40);
        const float4* k4 = (const float4*)(k3s + d3 * 40);
        float acc = 0.f;
#pragma unroll
        for (int t = 0; t < 10; ++t) {
            const float4 a = w4[t], b = k4[t];
            acc += a.x * b.x + a.y * b.y + a.z * b.z + a.w * b.w;
        }
        t1[i] = acc;
    }
    __syncthreads();

    for (int i = tid; i < 1280; i += 256) {
        const int d3 = i % 40, pd = i / 40;
        const int k1 = pd >> 3, d2 = pd & 7;
        float acc = 0.f;
#pragma unroll
        for (int k2 = 0; k2 < 8; ++k2) acc += t1[(k1 * 8 + k2) * 40 + d3] * k2s[d2 * 8 + k2];
        w0[i] = acc;
    }
    __syncthreads();

    for (int i = tid; i < 1280; i += 256) {
        const int d3 = i % 40, pd = i / 40;
        const int d1 = pd >> 3, d2 = pd & 7;
        float acc = 0.f;
#pragma unroll
        for (int k1 = 0; k1 < 4; ++k1) acc += w0[(k1 * 8 + d2) * 40 + d3] * k1s[d1 * 4 + k1];
        Wrot[(size_t)o * 1280 + i] = __float2bfloat16(acc);
    }
}

// ---------------------------------------------------------------------------
// Main GEMM r11: C[m,n] = sum_k A[m,k] * B[n,k]  (bf16 in, fp32 out/acc)
//
// r9 geometry/swizzle/grid, ONE barrier per K-tile (was 8).
//   Validated model from r9 counters: per-tile 5608 cyc predicted by
//   epoch-serialization (LDS-read epoch + MFMA epoch serialized at every
//   intra-tile barrier) vs 5800 measured. The intra-tile barriers were
//   self-inflicted: with dbuf, only the TILE-BOUNDARY barrier is required.
//   Without intra-tile barriers the 8 waves skew: one wave's ds_reads issue
//   while others occupy the MFMA pipe -> LDS pipe (2500 cyc/tile) drains
//   under the MFMA pipe (3100 cyc/tile).  m114 co-schedule mechanism,
//   in-block.
//
//   Safety ledger (1 barrier/iter, at iter END = tile boundary):
//   - WAR (stage t+1 overwrites buf[nxt] holding t-1): stages are issued
//     AFTER the boundary barrier; every ds_read of t-1 was consumed by an
//     MFMA before that barrier (compiler-forced lgkmcnt at use) -> no wave
//     passes the barrier with unsampled reads of t-1.  SAFE.
//   - RAW (reads of t+1 vs gload_lds writes of t+1): every wave drains its
//     own stages with vmcnt(0) BEFORE the boundary barrier (lead: issued at
//     iter start, waited after 80 MFMAs ~ 2500+ cyc >> HBM 900).  SAFE.
//   - Numerics: per-acc accumulation order (t asc, slice0 then slice1)
//     identical to r9 -> bitwise-identical output.
// ---------------------------------------------------------------------------
#define BM 256
#define BN 320
#define BK 64
#define AGRAN 2048   // BM*8 granules (16B each) per buffer = 32 KiB
#define BGRAN 2560   // BN*8 granules per buffer = 40 KiB

__global__ __launch_bounds__(512, 2)
void gemm_bt(const __hip_bfloat16* __restrict__ A,   // [M,K] bf16
             const __hip_bfloat16* __restrict__ B,   // [N,K] bf16
             float* __restrict__ C,                  // [M,N] fp32
             int M, int N, int K) {
    __shared__ bf16x8 As[2][AGRAN];   // 64 KiB
    __shared__ bf16x8 Bs[2][BGRAN];   // 80 KiB

    const int tid  = threadIdx.x;
    const int wave = tid >> 6;
    const int lane = tid & 63;
    const int q    = lane >> 4;
    const int r16  = lane & 15;
    const int wm   = wave >> 2;       // 0..1
    const int wn   = wave & 3;        // 0..3

    // XCD-partitioned tile assignment (grid = 64*4 = 256, 8 | 256)
    const int nTilesN = N / BN;               // 4
    const int chunkM  = (M / BM) >> 3;        // 8 M-tiles per XCD
    const int xcd = blockIdx.x & 7;
    const int s   = blockIdx.x >> 3;          // 0..31 within XCD
    const int bm  = xcd * chunkM + s / nTilesN;
    const int bn  = s % nTilesN;
    const int tileM = bm * BM, tileN = bn * BN;

    // Per-chunk global byte offsets.  chunk c covers granules [c*512,+512):
    // granule g: row m = g>>3, phys slot p = g&7 holds data k-granule
    // kv = p ^ (m&7)  (XOR swizzle folded into the SOURCE address).
    uint32_t aoff[4], boff[5];
#pragma unroll
    for (int c = 0; c < 4; ++c) {
        const int g = c * 512 + tid;
        const int m = g >> 3, kv = (g & 7) ^ (m & 7);
        aoff[c] = (uint32_t)(((tileM + m) * K + kv * 8) * 2);
    }
#pragma unroll
    for (int c = 0; c < 5; ++c) {
        const int g = c * 512 + tid;
        const int m = g >> 3, kv = (g & 7) ^ (m & 7);
        boff[c] = (uint32_t)(((tileN + m) * K + kv * 8) * 2);
    }
    const char* Abase = (const char*)A;
    const char* Bbase = (const char*)B;

    // LDS fragment granule indices for k-slice 0; k-slice 1 = idx ^ 4
    // (kv=4|q and q<4 => (4|q)^x == (q^x)^4 for any x in 0..7).
    int ai[8], bi[5];
#pragma unroll
    for (int i = 0; i < 8; ++i) {
        const int m = wm * 128 + i * 16 + r16;
        ai[i] = m * 8 + (q ^ (m & 7));
    }
#pragma unroll
    for (int j = 0; j < 5; ++j) {
        const int n = wn * 80 + j * 16 + r16;
        bi[j] = n * 8 + (q ^ (n & 7));
    }

    floatx4 acc[8][5];
#pragma unroll
    for (int i = 0; i < 8; ++i)
#pragma unroll
        for (int j = 0; j < 5; ++j) acc[i][j] = (floatx4){0.f, 0.f, 0.f, 0.f};

    const int nk = K / BK;                    // 20

    // Prologue: stage tile 0 (9 loads/thread), drain, barrier.
#pragma unroll
    for (int c = 0; c < 4; ++c)
        async_copy16(&As[0][c * 512 + wave * 64], Abase + aoff[c]);
#pragma unroll
    for (int c = 0; c < 5; ++c)
        async_copy16(&Bs[0][c * 512 + wave * 64], Bbase + boff[c]);
    asm volatile("s_waitcnt vmcnt(0)" ::: "memory");
    __builtin_amdgcn_s_barrier();

    for (int t = 0; t < nk; ++t) {
        const int cur = t & 1, nxt = cur ^ 1;
        const uint32_t kb = (uint32_t)((t + 1) * BK * 2);
        const bool hn = (t + 1 < nk);

        // stage tile t+1 first (vmem pipe starts earliest; buf[nxt] was
        // retired by the barrier we just crossed)
        if (hn) {
#pragma unroll
            for (int c = 0; c < 4; ++c)
                async_copy16(&As[nxt][c * 512 + wave * 64], Abase + aoff[c] + kb);
#pragma unroll
            for (int c = 0; c < 5; ++c)
                async_copy16(&Bs[nxt][c * 512 + wave * 64], Bbase + boff[c] + kb);
        }

        // slice-0 fragments + MFMAs; slice-1 reads follow with NO barrier
        // between -> waves skew, LDS pipe drains under the MFMA pipe.
        bf16x8 af0[8], bf0[5];
#pragma unroll
        for (int i = 0; i < 8; ++i) af0[i] = As[cur][ai[i]];
#pragma unroll
        for (int j = 0; j < 5; ++j) bf0[j] = Bs[cur][bi[j]];

        __builtin_amdgcn_s_setprio(1);
#pragma unroll
        for (int i = 0; i < 8; ++i)
#pragma unroll
            for (int j = 0; j < 5; ++j)
                acc[i][j] = __builtin_amdgcn_mfma_f32_16x16x32_bf16(
                    af0[i], bf0[j], acc[i][j], 0, 0, 0);
        __builtin_amdgcn_s_setprio(0);

        bf16x8 af1[8], bf1[5];
#pragma unroll
        for (int i = 0; i < 8; ++i) af1[i] = As[cur][ai[i] ^ 4];
#pragma unroll
        for (int j = 0; j < 5; ++j) bf1[j] = Bs[cur][bi[j] ^ 4];

        __builtin_amdgcn_s_setprio(1);
#pragma unroll
        for (int i = 0; i < 8; ++i)
#pragma unroll
            for (int j = 0; j < 5; ++j)
                acc[i][j] = __builtin_amdgcn_mfma_f32_16x16x32_bf16(
                    af1[i], bf1[j], acc[i][j], 0, 0, 0);
        __builtin_amdgcn_s_setprio(0);

        // Tile boundary: my stages of t+1 landed (vmcnt), then barrier.
        // ~2500+ cyc of lead on the vmcnt -> near-free.
        if (hn) {
            asm volatile("s_waitcnt vmcnt(0)" ::: "memory");
            __builtin_amdgcn_sched_barrier(0);
            __builtin_amdgcn_s_barrier();
            __builtin_amdgcn_sched_barrier(0);
        }
    }

    // epilogue: C/D layout col=lane&15, row=quad*4+reg (m89/m91)
#pragma unroll
    for (int i = 0; i < 8; ++i) {
#pragma unroll
        for (int j = 0; j < 5; ++j) {
            const int col = tileN + wn * 80 + j * 16 + r16;
#pragma unroll
            for (int r = 0; r < 4; ++r) {
                const int row = tileM + wm * 128 + i * 16 + q * 4 + r;
                C[(size_t)row * N + col] = acc[i][j][r];
            }
        }
    }
}

// ---------------------------------------------------------------------------
extern "C" void kernel_launch(void* const* d_in, const int* in_sizes, int n_in,
                              void* d_out, int out_size, void* d_ws, size_t ws_size,
                              hipStream_t stream) {
    const float* x  = (const float*)d_in[0];  // [4,4096,1280] fp32
    const float* W  = (const float*)d_in[1];  // [1280,1280]  fp32
    const float* K1 = (const float*)d_in[2];  // [4,4]
    const float* K2 = (const float*)d_in[3];  // [8,8]
    const float* K3 = (const float*)d_in[4];  // [40,40]
    float* out = (float*)d_out;               // [4,4096,1280] fp32

    const int D = 1280;
    const int M = in_sizes[0] / D;            // 16384
    const int N = D, K = D;

    // ws layout: [0, M*K) bf16 x ; then [+, N*K) bf16 Wrot
    __hip_bfloat16* x_bf = (__hip_bfloat16*)d_ws;
    __hip_bfloat16* Wrot = x_bf + (size_t)M * K;

    const int nConv = (M * K) / (256 * 8);    // 10240
    prep<<<nConv + D, 256, 0, stream>>>(x, W, K1, K2, K3, x_bf, Wrot, nConv);
    gemm_bt<<<(M / BM) * (N / BN), 512, 0, stream>>>(x_bf, Wrot, out, M, N, K);
}